// Round 1
// baseline (697.545 us; speedup 1.0000x reference)
//
#include <hip/hip_runtime.h>

typedef _Float16 f16;
typedef __attribute__((ext_vector_type(8))) _Float16 f16x8;
typedef __attribute__((ext_vector_type(4))) _Float16 f16x4;
typedef __attribute__((ext_vector_type(4))) float f32x4;

constexpr int B_ = 8, LQ = 1024, LK = 2048, NH = 16, HID = 1024;

// ---------- fp32 -> fp16 cast (vectorized) ----------
__global__ __launch_bounds__(256) void cvt_f32_f16(const float* __restrict__ src,
                                                   f16* __restrict__ dst, int n4) {
  int t = blockIdx.x * 256 + threadIdx.x;
  if (t >= n4) return;
  float4 v = ((const float4*)src)[t];
  f16x4 o = {(f16)v.x, (f16)v.y, (f16)v.z, (f16)v.w};
  ((f16x4*)dst)[t] = o;
}

// ---------- NT GEMM: C[M,N] = A[M,K] * B[N,K]^T, fp16 in, fp32 acc ----------
// 128x128 block tile, 4 waves in 2x2 (each wave 64x64 = 4x4 MFMA tiles), BK=64.
template <int OUT_F32>
__global__ __launch_bounds__(256) void gemm_bt(const f16* __restrict__ A,
                                               const f16* __restrict__ Bm,
                                               void* __restrict__ Cout,
                                               int M, int N, int K) {
  const int n0 = blockIdx.x * 128, m0 = blockIdx.y * 128;
  const int tid = threadIdx.x, lane = tid & 63, w = tid >> 6;
  const int wm = w >> 1, wn = w & 1;
  const int quad = lane >> 4, l16 = lane & 15;
  __shared__ __align__(16) f16 As[128 * 64];
  __shared__ __align__(16) f16 Bs[128 * 64];
  f32x4 acc[4][4] = {};
  for (int k0 = 0; k0 < K; k0 += 64) {
    __syncthreads();
#pragma unroll
    for (int p = 0; p < 4; ++p) {
      int r = (tid >> 3) + p * 32, s = tid & 7;
      *(uint4*)&As[r * 64 + s * 8] = *(const uint4*)&A[(size_t)(m0 + r) * K + k0 + s * 8];
      *(uint4*)&Bs[r * 64 + s * 8] = *(const uint4*)&Bm[(size_t)(n0 + r) * K + k0 + s * 8];
    }
    __syncthreads();
#pragma unroll
    for (int ks = 0; ks < 2; ++ks) {
      f16x8 af[4], bfr[4];
#pragma unroll
      for (int i = 0; i < 4; ++i) {
        af[i] = *(const f16x8*)&As[(wm * 64 + i * 16 + l16) * 64 + ks * 32 + quad * 8];
        bfr[i] = *(const f16x8*)&Bs[(wn * 64 + i * 16 + l16) * 64 + ks * 32 + quad * 8];
      }
#pragma unroll
      for (int i = 0; i < 4; ++i)
#pragma unroll
        for (int j = 0; j < 4; ++j)
          acc[i][j] = __builtin_amdgcn_mfma_f32_16x16x32_f16(af[i], bfr[j], acc[i][j], 0, 0, 0);
    }
  }
#pragma unroll
  for (int i = 0; i < 4; ++i)
#pragma unroll
    for (int j = 0; j < 4; ++j) {
      int row = m0 + wm * 64 + i * 16 + quad * 4;
      int col = n0 + wn * 64 + j * 16 + l16;
#pragma unroll
      for (int r = 0; r < 4; ++r) {
        float v = acc[i][j][r];
        if (OUT_F32)
          ((float*)Cout)[(size_t)(row + r) * N + col] = v;
        else
          ((f16*)Cout)[(size_t)(row + r) * N + col] = (f16)v;
      }
    }
}

// ---------- interleaved RoPE + repack to [B,H,L,64] ----------
// one thread per rotation pair (2i, 2i+1)
__global__ __launch_bounds__(256) void rope_pack(const f16* __restrict__ src,
                                                 f16* __restrict__ dst,
                                                 int L, int lg2L, int rowstride, int cspan) {
  int t = blockIdx.x * 256 + threadIdx.x;
  int i = t & 31;
  int h = (t >> 5) & 15;
  int l = (t >> 9) & (L - 1);
  int b = t >> (9 + lg2L);
  const f16* s = src + (size_t)(b * L + l) * rowstride + h * cspan + 2 * i;
  float x0 = (float)s[0], x1 = (float)s[1];
  // 1/theta = 10000^(-i/32) = 2^(-log2(10000)/32 * i)
  float inv_theta = exp2f((float)i * -0.41524101186091903f);
  float ang = (float)l * inv_theta;
  float sn, cs;
  sincosf(ang, &sn, &cs);
  float o0 = x0 * cs - x1 * sn;
  float o1 = x1 * cs + x0 * sn;
  f16* d = dst + ((size_t)(b * NH + h) * L + l) * 64 + 2 * i;
  d[0] = (f16)o0;
  d[1] = (f16)o1;
}

// ---------- flash attention ----------
// grid (LQ/64, B*NH), 256 threads (4 waves). Each wave: 16 q-rows x full D=64.
// Qb [bh][lq][64], Kb [bh][lk][64] (RoPE applied), V read from KVraw [b][lk][h*128+64+dv].
__global__ __launch_bounds__(256) void attn(const f16* __restrict__ Qb,
                                            const f16* __restrict__ Kb,
                                            const f16* __restrict__ KVraw,
                                            f16* __restrict__ attnb) {
  const int bh = blockIdx.y, b = bh >> 4, h = bh & 15;
  const int q0 = blockIdx.x * 64;
  const int tid = threadIdx.x, lane = tid & 63, w = tid >> 6;
  const int quad = lane >> 4, l16 = lane & 15;
  __shared__ __align__(16) f16 Ks[64 * 64];
  __shared__ __align__(16) f16 Vts[64 * 80];  // V transposed (dv, kcol), stride 80
  __shared__ __align__(16) f16 Ps[4][16 * 64];
  // Q A-fragments: m=l16 -> q row, k=quad*8+j -> d
  const f16* qptr = Qb + ((size_t)bh * LQ + q0 + 16 * w + l16) * 64;
  f16x8 qf0 = *(const f16x8*)&qptr[quad * 8];
  f16x8 qf1 = *(const f16x8*)&qptr[32 + quad * 8];
  f32x4 o[4] = {};
  float m_run[4], l_run[4];
#pragma unroll
  for (int r = 0; r < 4; ++r) { m_run[r] = -1e30f; l_run[r] = 0.f; }
  const f16* kbase = Kb + (size_t)bh * LK * 64;
  const f16* vbase = KVraw + (size_t)b * LK * 2048 + h * 128 + 64;
  for (int c = 0; c < LK / 64; ++c) {
    int kc0 = c * 64;
    __syncthreads();
#pragma unroll
    for (int p = 0; p < 2; ++p) {
      int r = (tid >> 3) + p * 32, s = tid & 7;
      *(uint4*)&Ks[r * 64 + s * 8] = *(const uint4*)&kbase[(size_t)(kc0 + r) * 64 + s * 8];
      f16x8 vv = *(const f16x8*)&vbase[(size_t)(kc0 + r) * 2048 + s * 8];
#pragma unroll
      for (int j = 0; j < 8; ++j) Vts[(s * 8 + j) * 80 + r] = vv[j];
    }
    __syncthreads();
    // S = Q K^T : A=Q (m=q,k=d), B[k=d][n=kcol] = K[kcol][d]
    f32x4 sacc[4] = {};
#pragma unroll
    for (int nt = 0; nt < 4; ++nt) {
      f16x8 kf0 = *(const f16x8*)&Ks[(nt * 16 + l16) * 64 + quad * 8];
      f16x8 kf1 = *(const f16x8*)&Ks[(nt * 16 + l16) * 64 + 32 + quad * 8];
      sacc[nt] = __builtin_amdgcn_mfma_f32_16x16x32_f16(qf0, kf0, sacc[nt], 0, 0, 0);
      sacc[nt] = __builtin_amdgcn_mfma_f32_16x16x32_f16(qf1, kf1, sacc[nt], 0, 0, 0);
    }
    // online softmax; C/D layout: row = quad*4+r, col = nt*16+l16
    float p_[4][4];
#pragma unroll
    for (int r = 0; r < 4; ++r) {
      float mx = fmaxf(fmaxf(sacc[0][r], sacc[1][r]), fmaxf(sacc[2][r], sacc[3][r]));
#pragma unroll
      for (int d = 1; d < 16; d <<= 1) mx = fmaxf(mx, __shfl_xor(mx, d, 64));
      float mn = fmaxf(m_run[r], mx);
      float al = __expf(m_run[r] - mn);
      m_run[r] = mn;
      float ps = 0.f;
#pragma unroll
      for (int nt = 0; nt < 4; ++nt) {
        p_[nt][r] = __expf(sacc[nt][r] - mn);
        ps += p_[nt][r];
      }
#pragma unroll
      for (int d = 1; d < 16; d <<= 1) ps += __shfl_xor(ps, d, 64);
      l_run[r] = l_run[r] * al + ps;
#pragma unroll
      for (int dt = 0; dt < 4; ++dt) o[dt][r] *= al;
    }
    // P: C/D layout -> LDS -> A layout (per-wave private region, no barrier needed)
#pragma unroll
    for (int nt = 0; nt < 4; ++nt)
#pragma unroll
      for (int r = 0; r < 4; ++r)
        Ps[w][(quad * 4 + r) * 64 + nt * 16 + l16] = (f16)p_[nt][r];
    f16x8 pf0 = *(const f16x8*)&Ps[w][l16 * 64 + quad * 8];
    f16x8 pf1 = *(const f16x8*)&Ps[w][l16 * 64 + 32 + quad * 8];
    // O += P V : B[k=kcol][n=dv] = Vts[dv][kcol]
#pragma unroll
    for (int dt = 0; dt < 4; ++dt) {
      f16x8 vf0 = *(const f16x8*)&Vts[(dt * 16 + l16) * 80 + quad * 8];
      f16x8 vf1 = *(const f16x8*)&Vts[(dt * 16 + l16) * 80 + 32 + quad * 8];
      o[dt] = __builtin_amdgcn_mfma_f32_16x16x32_f16(pf0, vf0, o[dt], 0, 0, 0);
      o[dt] = __builtin_amdgcn_mfma_f32_16x16x32_f16(pf1, vf1, o[dt], 0, 0, 0);
    }
  }
  // epilogue: normalize and write [B,LQ,H,64] (= [B*LQ, 1024])
#pragma unroll
  for (int dt = 0; dt < 4; ++dt)
#pragma unroll
    for (int r = 0; r < 4; ++r) {
      int q = q0 + 16 * w + quad * 4 + r;
      int dv = dt * 16 + l16;
      float val = o[dt][r] / l_run[r];
      attnb[((size_t)b * LQ + q) * HID + h * 64 + dv] = (f16)val;
    }
}

extern "C" void kernel_launch(void* const* d_in, const int* in_sizes, int n_in,
                              void* d_out, int out_size, void* d_ws, size_t ws_size,
                              hipStream_t stream) {
  const float* x = (const float*)d_in[0];
  const float* y = (const float*)d_in[1];
  const float* Wq = (const float*)d_in[2];
  const float* Wkv = (const float*)d_in[3];
  const float* Wo = (const float*)d_in[4];
  float* out = (float*)d_out;

  char* p = (char*)d_ws;
  f16* xb = (f16*)p;    p += (size_t)B_ * LQ * HID * 2;      // 16 MB
  f16* yb = (f16*)p;    p += (size_t)B_ * LK * HID * 2;      // 32 MB
  f16* Wqb = (f16*)p;   p += (size_t)HID * HID * 2;          // 2 MB
  f16* Wkvb = (f16*)p;  p += (size_t)2 * HID * HID * 2;      // 4 MB
  f16* Wob = (f16*)p;   p += (size_t)HID * HID * 2;          // 2 MB
  f16* Qraw = (f16*)p;  p += (size_t)B_ * LQ * HID * 2;      // 16 MB
  f16* KVraw = (f16*)p; p += (size_t)B_ * LK * 2 * HID * 2;  // 64 MB
  // aliased buffers (lifetimes disjoint):
  f16* Qb = xb;     // xb dead after GEMM1
  f16* Kb = yb;     // yb dead after GEMM2
  f16* attnb = Qraw;  // Qraw dead after rope_pack(Q)

  auto cvt = [&](const float* s, f16* d, size_t n) {
    cvt_f32_f16<<<dim3((unsigned)((n / 4 + 255) / 256)), 256, 0, stream>>>(s, d, (int)(n / 4));
  };
  cvt(x, xb, (size_t)B_ * LQ * HID);
  cvt(y, yb, (size_t)B_ * LK * HID);
  cvt(Wq, Wqb, (size_t)HID * HID);
  cvt(Wkv, Wkvb, (size_t)2 * HID * HID);
  cvt(Wo, Wob, (size_t)HID * HID);

  // Q = x @ Wq^T  -> Qraw [B*LQ, 1024] fp16
  gemm_bt<0><<<dim3(HID / 128, B_ * LQ / 128), 256, 0, stream>>>(xb, Wqb, Qraw, B_ * LQ, HID, HID);
  // KV = y @ Wkv^T -> KVraw [B*LK, 2048] fp16
  gemm_bt<0><<<dim3(2 * HID / 128, B_ * LK / 128), 256, 0, stream>>>(yb, Wkvb, KVraw, B_ * LK, 2 * HID, HID);

  // RoPE + repack
  rope_pack<<<dim3(B_ * LQ * NH * 32 / 256), 256, 0, stream>>>(Qraw, Qb, LQ, 10, 1024, 64);
  rope_pack<<<dim3(B_ * LK * NH * 32 / 256), 256, 0, stream>>>(KVraw, Kb, LK, 11, 2048, 128);

  // attention -> attnb [B*LQ, 1024] fp16
  attn<<<dim3(LQ / 64, B_ * NH), 256, 0, stream>>>(Qb, Kb, KVraw, attnb);

  // out = attn @ Wo^T -> fp32
  gemm_bt<1><<<dim3(HID / 128, B_ * LQ / 128), 256, 0, stream>>>(attnb, Wob, out, B_ * LQ, HID, HID);
}

// Round 2
// 507.482 us; speedup vs baseline: 1.3745x; 1.3745x over previous
//
#include <hip/hip_runtime.h>

typedef _Float16 f16;
typedef __attribute__((ext_vector_type(8))) _Float16 f16x8;
typedef __attribute__((ext_vector_type(4))) _Float16 f16x4;
typedef __attribute__((ext_vector_type(4))) float f32x4;

constexpr int B_ = 8, LQ = 1024, LK = 2048, NH = 16, HID = 1024;

// async global->LDS, 16B per lane; LDS dest must be wave-uniform base + lane*16
__device__ __forceinline__ void gll16(const void* g, void* l) {
  __builtin_amdgcn_global_load_lds((const __attribute__((address_space(1))) void*)g,
                                   (__attribute__((address_space(3))) void*)l, 16, 0, 0);
}

// ---------- fp32 -> fp16 cast (vectorized) ----------
__global__ __launch_bounds__(256) void cvt_f32_f16(const float* __restrict__ src,
                                                   f16* __restrict__ dst, int n4) {
  int t = blockIdx.x * 256 + threadIdx.x;
  if (t >= n4) return;
  float4 v = ((const float4*)src)[t];
  f16x4 o = {(f16)v.x, (f16)v.y, (f16)v.z, (f16)v.w};
  ((f16x4*)dst)[t] = o;
}

// ---------- fused NT GEMM: C[M,N] = A[M,K] * B[N,K]^T ----------
// MODE 0: Q proj -> RoPE -> Qb [bh][lq][64]           (out0=Qb)
// MODE 1: KV proj -> wn=0: RoPE K -> Kb [bh][lk][64]; wn=1: V^T -> Vt [bh][kc][dv][64]
// MODE 2: plain fp32 output (out0)
template <int MODE>
__global__ __launch_bounds__(256) void gemm_fused(const f16* __restrict__ A,
                                                  const f16* __restrict__ Bm,
                                                  void* __restrict__ out0,
                                                  void* __restrict__ out1,
                                                  int M, int N, int K) {
  const int n0 = blockIdx.x * 128, m0 = blockIdx.y * 128;
  const int tid = threadIdx.x, lane = tid & 63, w = tid >> 6;
  const int wm = w >> 1, wn = w & 1;
  const int quad = lane >> 4, l16 = lane & 15;
  __shared__ __align__(16) f16 As[128 * 64];
  __shared__ __align__(16) f16 Bs[128 * 64];
  f32x4 acc[4][4] = {};
  const int sr = tid >> 3, sc = (tid & 7) * 8;
  const f16* ga = A + (size_t)(m0 + sr) * K + sc;
  const f16* gb = Bm + (size_t)(n0 + sr) * K + sc;
  for (int k0 = 0; k0 < K; k0 += 64) {
    __syncthreads();
#pragma unroll
    for (int p = 0; p < 4; ++p) {
      gll16(ga + (size_t)p * 32 * K + k0, &As[(sr + p * 32) * 64 + sc]);
      gll16(gb + (size_t)p * 32 * K + k0, &Bs[(sr + p * 32) * 64 + sc]);
    }
    __syncthreads();
#pragma unroll
    for (int ks = 0; ks < 2; ++ks) {
      f16x8 af[4], bfr[4];
#pragma unroll
      for (int i = 0; i < 4; ++i) {
        af[i] = *(const f16x8*)&As[(wm * 64 + i * 16 + l16) * 64 + ks * 32 + quad * 8];
        bfr[i] = *(const f16x8*)&Bs[(wn * 64 + i * 16 + l16) * 64 + ks * 32 + quad * 8];
      }
#pragma unroll
      for (int i = 0; i < 4; ++i)
#pragma unroll
        for (int j = 0; j < 4; ++j)
          acc[i][j] = __builtin_amdgcn_mfma_f32_16x16x32_f16(af[i], bfr[j], acc[i][j], 0, 0, 0);
    }
  }
  if (MODE == 2) {
#pragma unroll
    for (int i = 0; i < 4; ++i)
#pragma unroll
      for (int j = 0; j < 4; ++j) {
        int row = m0 + wm * 64 + i * 16 + quad * 4;
        int col = n0 + wn * 64 + j * 16 + l16;
#pragma unroll
        for (int r = 0; r < 4; ++r)
          ((float*)out0)[(size_t)(row + r) * N + col] = acc[i][j][r];
      }
    return;
  }
  constexpr int LSH = (MODE == 0) ? 10 : 11;
  constexpr int LMSK = (MODE == 0) ? 1023 : 2047;
  const int Ltok = LMSK + 1;
  if (MODE == 0 || wn == 0) {
    // RoPE path. col c: head h = c / headspan, d = (c per-head K-dim index)
#pragma unroll
    for (int j = 0; j < 4; ++j) {
      int c = n0 + wn * 64 + j * 16 + l16;
      int h = (MODE == 0) ? (c >> 6) : (n0 >> 7);
      int d = (MODE == 0) ? (c & 63) : (j * 16 + l16);
      float inv_t = exp2f((float)(d >> 1) * -0.41524101186091903f);
#pragma unroll
      for (int i = 0; i < 4; ++i) {
        f32x4 v = acc[i][j];
        f32x4 pv;
#pragma unroll
        for (int r = 0; r < 4; ++r) pv[r] = __shfl_xor(v[r], 1, 64);
        int row0 = m0 + wm * 64 + i * 16 + quad * 4;
#pragma unroll
        for (int r = 0; r < 4; ++r) {
          int row = row0 + r;
          int pos = row & LMSK, b = row >> LSH;
          float ang = (float)pos * inv_t;
          float sn, cs;
          __sincosf(ang, &sn, &cs);
          float o = (d & 1) ? (v[r] * cs + pv[r] * sn) : (v[r] * cs - pv[r] * sn);
          ((f16*)out0)[(((size_t)b * NH + h) * Ltok + pos) * 64 + d] = (f16)o;
        }
      }
    }
  } else {
    // V path (MODE 1, wn==1): write V^T tiled: Vt[((bh*32 + kc)*64 + dv)*64 + klo]
    const int h = n0 >> 7;
#pragma unroll
    for (int j = 0; j < 4; ++j) {
      int dv = j * 16 + l16;
#pragma unroll
      for (int i = 0; i < 4; ++i) {
        int row0 = m0 + wm * 64 + i * 16 + quad * 4;
        int pos0 = row0 & 2047, b = row0 >> 11;
        int kc = pos0 >> 6, klo = pos0 & 63;
        f32x4 v = acc[i][j];
        f16x4 pk = {(f16)v[0], (f16)v[1], (f16)v[2], (f16)v[3]};
        *(f16x4*)&((f16*)out1)[((((size_t)b * NH + h) * 32 + kc) * 64 + dv) * 64 + klo] = pk;
      }
    }
  }
}

// ---------- flash attention ----------
// grid (LQ/64, B*NH), 256 threads (4 waves). Each wave: 16 q-rows x full D=64.
// Qb/Kb [bh][l][64] (RoPE applied), Vt [bh][kchunk][dv][64] (pre-transposed).
__global__ __launch_bounds__(256) void attn(const f16* __restrict__ Qb,
                                            const f16* __restrict__ Kb,
                                            const f16* __restrict__ Vt,
                                            f16* __restrict__ attnb) {
  const int bh = blockIdx.y, b = bh >> 4, h = bh & 15;
  const int q0 = blockIdx.x * 64;
  const int tid = threadIdx.x, lane = tid & 63, w = tid >> 6;
  const int quad = lane >> 4, l16 = lane & 15;
  // padded rows: 72 f16 = 36 words -> frag-read start bank 4*(l16+quad)%32 (floor)
  __shared__ __align__(16) f16 Ks[64 * 72];
  __shared__ __align__(16) f16 Vts[64 * 72];
  __shared__ __align__(16) f16 Ps[4][16 * 72];
  const f16* qptr = Qb + ((size_t)bh * LQ + q0 + 16 * w + l16) * 64;
  f16x8 qf0 = *(const f16x8*)&qptr[quad * 8];
  f16x8 qf1 = *(const f16x8*)&qptr[32 + quad * 8];
  f16x8 onesv;
#pragma unroll
  for (int j = 0; j < 8; ++j) onesv[j] = (f16)1.0f;
  f32x4 o[4] = {};
  f32x4 lacc = {};
  float m_run[4];
#pragma unroll
  for (int r = 0; r < 4; ++r) m_run[r] = -1e30f;
  const f16* kbase = Kb + (size_t)bh * LK * 64;
  const f16* vtb = Vt + (size_t)bh * 32 * 4096;
  for (int c = 0; c < LK / 64; ++c) {
    int kc0 = c * 64;
    __syncthreads();
#pragma unroll
    for (int p = 0; p < 2; ++p) {
      int r = (tid >> 3) + p * 32, s = tid & 7;
      *(uint4*)&Ks[r * 72 + s * 8] = *(const uint4*)&kbase[(size_t)(kc0 + r) * 64 + s * 8];
      *(uint4*)&Vts[r * 72 + s * 8] = *(const uint4*)&vtb[(size_t)(c * 64 + r) * 64 + s * 8];
    }
    __syncthreads();
    // S = Q K^T
    f32x4 sacc[4] = {};
#pragma unroll
    for (int nt = 0; nt < 4; ++nt) {
      f16x8 kf0 = *(const f16x8*)&Ks[(nt * 16 + l16) * 72 + quad * 8];
      f16x8 kf1 = *(const f16x8*)&Ks[(nt * 16 + l16) * 72 + 32 + quad * 8];
      sacc[nt] = __builtin_amdgcn_mfma_f32_16x16x32_f16(qf0, kf0, sacc[nt], 0, 0, 0);
      sacc[nt] = __builtin_amdgcn_mfma_f32_16x16x32_f16(qf1, kf1, sacc[nt], 0, 0, 0);
    }
    // online max update; C/D layout: row = quad*4+r, col = nt*16+l16
#pragma unroll
    for (int r = 0; r < 4; ++r) {
      float mx = fmaxf(fmaxf(sacc[0][r], sacc[1][r]), fmaxf(sacc[2][r], sacc[3][r]));
#pragma unroll
      for (int d = 1; d < 16; d <<= 1) mx = fmaxf(mx, __shfl_xor(mx, d, 64));
      float mn = fmaxf(m_run[r], mx);
      float al = __expf(m_run[r] - mn);
      m_run[r] = mn;
      lacc[r] *= al;
#pragma unroll
      for (int dt = 0; dt < 4; ++dt) o[dt][r] *= al;
#pragma unroll
      for (int nt = 0; nt < 4; ++nt)
        Ps[w][(quad * 4 + r) * 72 + nt * 16 + l16] = (f16)__expf(sacc[nt][r] - mn);
    }
    f16x8 pf0 = *(const f16x8*)&Ps[w][l16 * 72 + quad * 8];
    f16x8 pf1 = *(const f16x8*)&Ps[w][l16 * 72 + 32 + quad * 8];
    // row-sum of P via ones-MFMA (same layout as o)
    lacc = __builtin_amdgcn_mfma_f32_16x16x32_f16(pf0, onesv, lacc, 0, 0, 0);
    lacc = __builtin_amdgcn_mfma_f32_16x16x32_f16(pf1, onesv, lacc, 0, 0, 0);
    // O += P V
#pragma unroll
    for (int dt = 0; dt < 4; ++dt) {
      f16x8 vf0 = *(const f16x8*)&Vts[(dt * 16 + l16) * 72 + quad * 8];
      f16x8 vf1 = *(const f16x8*)&Vts[(dt * 16 + l16) * 72 + 32 + quad * 8];
      o[dt] = __builtin_amdgcn_mfma_f32_16x16x32_f16(pf0, vf0, o[dt], 0, 0, 0);
      o[dt] = __builtin_amdgcn_mfma_f32_16x16x32_f16(pf1, vf1, o[dt], 0, 0, 0);
    }
  }
#pragma unroll
  for (int dt = 0; dt < 4; ++dt)
#pragma unroll
    for (int r = 0; r < 4; ++r) {
      int q = q0 + 16 * w + quad * 4 + r;
      int dv = dt * 16 + l16;
      attnb[((size_t)b * LQ + q) * HID + h * 64 + dv] = (f16)(o[dt][r] / lacc[r]);
    }
}

extern "C" void kernel_launch(void* const* d_in, const int* in_sizes, int n_in,
                              void* d_out, int out_size, void* d_ws, size_t ws_size,
                              hipStream_t stream) {
  const float* x = (const float*)d_in[0];
  const float* y = (const float*)d_in[1];
  const float* Wq = (const float*)d_in[2];
  const float* Wkv = (const float*)d_in[3];
  const float* Wo = (const float*)d_in[4];
  float* out = (float*)d_out;

  char* p = (char*)d_ws;
  f16* xb = (f16*)p;    p += (size_t)B_ * LQ * HID * 2;      // 16 MB
  f16* yb = (f16*)p;    p += (size_t)B_ * LK * HID * 2;      // 32 MB
  f16* Wqb = (f16*)p;   p += (size_t)HID * HID * 2;          // 2 MB
  f16* Wkvb = (f16*)p;  p += (size_t)2 * HID * HID * 2;      // 4 MB
  f16* Wob = (f16*)p;   p += (size_t)HID * HID * 2;          // 2 MB
  f16* Qb = (f16*)p;    p += (size_t)B_ * LQ * HID * 2;      // 16 MB
  f16* Kb = (f16*)p;    p += (size_t)B_ * LK * HID * 2;      // 32 MB
  f16* Vt = (f16*)p;    p += (size_t)B_ * LK * HID * 2;      // 32 MB
  f16* attnb = xb;  // xb dead after GEMM1

  auto cvt = [&](const float* s, f16* d, size_t n) {
    cvt_f32_f16<<<dim3((unsigned)((n / 4 + 255) / 256)), 256, 0, stream>>>(s, d, (int)(n / 4));
  };
  cvt(x, xb, (size_t)B_ * LQ * HID);
  cvt(y, yb, (size_t)B_ * LK * HID);
  cvt(Wq, Wqb, (size_t)HID * HID);
  cvt(Wkv, Wkvb, (size_t)2 * HID * HID);
  cvt(Wo, Wob, (size_t)HID * HID);

  // Q = RoPE(x @ Wq^T) -> Qb [bh][lq][64]
  gemm_fused<0><<<dim3(HID / 128, B_ * LQ / 128), 256, 0, stream>>>(
      xb, Wqb, Qb, nullptr, B_ * LQ, HID, HID);
  // KV = y @ Wkv^T -> Kb (RoPE) + Vt (transposed, chunk-tiled)
  gemm_fused<1><<<dim3(2 * HID / 128, B_ * LK / 128), 256, 0, stream>>>(
      yb, Wkvb, Kb, Vt, B_ * LK, 2 * HID, HID);

  // attention -> attnb [B*LQ, 1024] fp16
  attn<<<dim3(LQ / 64, B_ * NH), 256, 0, stream>>>(Qb, Kb, Vt, attnb);

  // out = attn @ Wo^T -> fp32
  gemm_fused<2><<<dim3(HID / 128, B_ * LQ / 128), 256, 0, stream>>>(
      attnb, Wob, out, nullptr, B_ * LQ, HID, HID);
}